// Round 1
// 412.724 us; speedup vs baseline: 1.0451x; 1.0451x over previous
//
#include <hip/hip_runtime.h>
#include <hip/hip_bf16.h>

constexpr int kN = 8192;
constexpr int kD = 128;
constexpr int kV = 3;
constexpr int kNV = kV * kN;
constexpr int kNChunk = 512;             // n columns per k_main block
constexpr int kNTile = 32;               // n per iteration (2 MFMA n-subtiles)
constexpr int kIters = kNChunk / kNTile; // 16
constexpr int kAccStride = 529;          // odd stride: the 3 view-rows land on distinct banks
constexpr float kLn2 = 0.6931471805599453f;
// Hc scale = (1/T)/ln2 so that MFMA dot is already in log2 domain: exp(sim/T) == exp2(dot)
constexpr float kScaleHc = 2.885390081777927f;

typedef __attribute__((ext_vector_type(8))) short bf16x8;
typedef __attribute__((ext_vector_type(4))) float floatx4;

#if __has_builtin(__builtin_amdgcn_exp2f)
#define EXP2F(x) __builtin_amdgcn_exp2f(x)
#else
#define EXP2F(x) exp2f(x)
#endif

__device__ __forceinline__ unsigned pack_bf16(float a, float b) {
    unsigned ua = __float_as_uint(a);
    unsigned ub = __float_as_uint(b);
    ua = (ua + 0x7FFFu + ((ua >> 16) & 1u)) >> 16;   // RNE round to bf16
    ub = (ub + 0x7FFFu + ((ub >> 16) & 1u)) >> 16;
    return ua | (ub << 16);
}

// Sum over the 4 quads (lanes l, l^16, l^32, l^48) without touching the LDS pipe:
// register-copy + permlane*_swap implements the butterfly in pure VALU.
__device__ __forceinline__ float quad_sum(float p) {
    float t = p;
    asm("v_permlane16_swap_b32 %0, %1" : "+v"(p), "+v"(t));  // l <-> l^16 exchange
    p += t;
    t = p;
    asm("v_permlane32_swap_b32 %0, %1" : "+v"(p), "+v"(t));  // l <-> l^32 exchange
    return p + t;
}

// One wave per row. Rows [0,kN): Hc (scale (1/T)/ln2 folded). Rows [kN, kN+kV*kN): Hv flat.
__global__ void k_normalize(const float* __restrict__ Hc, const float* __restrict__ Hv,
                            unsigned* __restrict__ HcB, unsigned* __restrict__ HvB) {
    int row  = (blockIdx.x * blockDim.x + threadIdx.x) >> 6;
    int lane = threadIdx.x & 63;
    const float* src;
    unsigned* dst;
    float extra;
    if (row < kN) { src = Hc + (size_t)row * kD; dst = HcB + (size_t)row * (kD / 2); extra = kScaleHc; }
    else {
        int r = row - kN;
        src = Hv + (size_t)r * kD; dst = HvB + (size_t)r * (kD / 2); extra = 1.0f;
    }
    float2 x = ((const float2*)src)[lane];
    float ss = x.x * x.x + x.y * x.y;
    ss += __shfl_xor(ss, 1);  ss += __shfl_xor(ss, 2);  ss += __shfl_xor(ss, 4);
    ss += __shfl_xor(ss, 8);  ss += __shfl_xor(ss, 16); ss += __shfl_xor(ss, 32);
    float inv = extra * rsqrtf(fmaxf(ss, 1e-24f));
    dst[lane] = pack_bf16(x.x * inv, x.y * inv);
}

// One wave per (v,n). Raw dot (carries 2/ln2 scale) scattered into 256 partial slots.
__global__ void k_positive(const unsigned* __restrict__ HcB, const unsigned* __restrict__ HvB,
                           float* __restrict__ pos_partial) {
    int row  = (blockIdx.x * blockDim.x + threadIdx.x) >> 6;  // v*kN + n
    int lane = threadIdx.x & 63;
    int w    = threadIdx.x >> 6;
    int n    = row & (kN - 1);
    unsigned a = HcB[(size_t)n * (kD / 2) + lane];
    unsigned b = HvB[(size_t)row * (kD / 2) + lane];
    float dot = __uint_as_float(a << 16) * __uint_as_float(b << 16)
              + __uint_as_float(a & 0xFFFF0000u) * __uint_as_float(b & 0xFFFF0000u);
    dot += __shfl_xor(dot, 1);  dot += __shfl_xor(dot, 2);  dot += __shfl_xor(dot, 4);
    dot += __shfl_xor(dot, 8);  dot += __shfl_xor(dot, 16); dot += __shfl_xor(dot, 32);
    __shared__ float acc4[4];
    if (lane == 0) acc4[w] = dot;
    __syncthreads();
    if (threadIdx.x == 0)
        atomicAdd(&pos_partial[blockIdx.x & 255], acc4[0] + acc4[1] + acc4[2] + acc4[3]);
}

// Double-buffered Hc LDS pipeline; S streamed straight into per-lane registers
// (prefetched one iteration ahead — each lane's 4 weights are a contiguous float4).
// Per iter: MFMA from LDS, exp2*(1-S), VALU permlane reduce, LDS-atomic denom partials.
// One barrier per iter; flush once at block end.
__launch_bounds__(256, 3)
__global__ void k_main(const unsigned* __restrict__ HcB, const unsigned* __restrict__ HvB,
                       const float* __restrict__ S, float* __restrict__ denom) {
    __shared__ short Htile[2][kNTile * 136];   // 136-short row stride (272B, 16B aligned)
    __shared__ float accum[kV * kAccStride];

    const int tid  = threadIdx.x;
    const int w    = tid >> 6;
    const int lane = tid & 63;
    const int col  = lane & 15;
    const int quad = lane >> 4;
    const int m0b  = blockIdx.x * 64;
    const int m0w  = m0b + w * 16;
    const int nbase = blockIdx.y * kNChunk;
    const int sr = tid >> 4;      // staging row 0..15 (and +16)
    const int sc = tid & 15;      // staging 16B chunk

    for (int i = tid; i < kV * kAccStride; i += 256) accum[i] = 0.f;

    // Persistent A fragments: A[m=lane&15][k=quad*8+j]
    bf16x8 afrag[kV][4];
#pragma unroll
    for (int v = 0; v < kV; ++v) {
        const short* rowp = (const short*)HvB + ((size_t)(v * kN + m0w + col)) * kD;
#pragma unroll
        for (int kk = 0; kk < 4; ++kk)
            afrag[v][kk] = *(const bf16x8*)(rowp + kk * 32 + quad * 8);
    }

    const short* hc = (const short*)HcB;
    // per-lane S base: row (nbase+col), cols m0w + quad*4 .. +3 (16B aligned)
    const float* Sp = S + (size_t)(nbase + col) * kN + m0b + (w << 4) + (quad << 2);

    // preload Hc tile 0 into LDS; prefetch iter-0 S into registers
    {
        float4 ha = *(const float4*)(hc + (size_t)(nbase + sr) * kD + sc * 8);
        float4 hb = *(const float4*)(hc + (size_t)(nbase + sr + 16) * kD + sc * 8);
        *(float4*)&Htile[0][sr * 136 + sc * 8]        = ha;
        *(float4*)&Htile[0][(sr + 16) * 136 + sc * 8] = hb;
    }
    float4 s0 = *(const float4*)(Sp);
    float4 s1 = *(const float4*)(Sp + (size_t)16 * kN);
    __syncthreads();

    for (int it = 0; it < kIters; ++it) {
        // issue next tile's loads (clamped re-read on last iter; L2-hot, harmless)
        int itn = (it + 1 < kIters) ? it + 1 : it;
        int n0n = nbase + itn * kNTile;
        float4 ha  = *(const float4*)(hc + (size_t)(n0n + sr) * kD + sc * 8);
        float4 hb  = *(const float4*)(hc + (size_t)(n0n + sr + 16) * kD + sc * 8);
        float4 s0n = *(const float4*)(Sp + (size_t)(itn * 32) * kN);
        float4 s1n = *(const float4*)(Sp + (size_t)(itn * 32 + 16) * kN);

        const int cur = it & 1;
#pragma unroll
        for (int sub = 0; sub < 2; ++sub) {
            const int nrow = sub * 16 + col;
            bf16x8 bfrag[4];
#pragma unroll
            for (int kk = 0; kk < 4; ++kk)
                bfrag[kk] = *(const bf16x8*)&Htile[cur][nrow * 136 + kk * 32 + quad * 8];
            float4 s4 = sub ? s1 : s0;

            floatx4 acc0 = {0.f,0.f,0.f,0.f}, acc1 = {0.f,0.f,0.f,0.f}, acc2 = {0.f,0.f,0.f,0.f};
#pragma unroll
            for (int kk = 0; kk < 4; ++kk) {
                acc0 = __builtin_amdgcn_mfma_f32_16x16x32_bf16(afrag[0][kk], bfrag[kk], acc0, 0, 0, 0);
                acc1 = __builtin_amdgcn_mfma_f32_16x16x32_bf16(afrag[1][kk], bfrag[kk], acc1, 0, 0, 0);
                acc2 = __builtin_amdgcn_mfma_f32_16x16x32_bf16(afrag[2][kk], bfrag[kk], acc2, 0, 0, 0);
            }
            float w0 = 1.f - s4.x, w1 = 1.f - s4.y, w2 = 1.f - s4.z, w3 = 1.f - s4.w;
            float p0 = w0 * EXP2F(acc0[0]) + w1 * EXP2F(acc0[1]) + w2 * EXP2F(acc0[2]) + w3 * EXP2F(acc0[3]);
            float p1 = w0 * EXP2F(acc1[0]) + w1 * EXP2F(acc1[1]) + w2 * EXP2F(acc1[2]) + w3 * EXP2F(acc1[3]);
            float p2 = w0 * EXP2F(acc2[0]) + w1 * EXP2F(acc2[1]) + w2 * EXP2F(acc2[2]) + w3 * EXP2F(acc2[3]);
            p0 = quad_sum(p0);
            p1 = quad_sum(p1);
            p2 = quad_sum(p2);
            float val = (quad == 0) ? p0 : ((quad == 1) ? p1 : p2);
            if (quad < 3)
                atomicAdd(&accum[quad * kAccStride + it * kNTile + sub * 16 + col], val);
        }

        s0 = s0n; s1 = s1n;
        const int nxt = cur ^ 1;
        *(float4*)&Htile[nxt][sr * 136 + sc * 8]        = ha;
        *(float4*)&Htile[nxt][(sr + 16) * 136 + sc * 8] = hb;
        __syncthreads();
    }

    for (int i = tid; i < kV * kNChunk; i += 256) {
        int v = i >> 9, c = i & (kNChunk - 1);
        atomicAdd(&denom[(size_t)v * kN + nbase + c], accum[v * kAccStride + c]);
    }
}

__global__ void k_final(const float* __restrict__ denom, const float* __restrict__ pos_partial,
                        float* __restrict__ out) {
    int idx  = blockIdx.x * 256 + threadIdx.x;   // 0..kNV-1
    int lane = threadIdx.x & 63;
    int w    = threadIdx.x >> 6;
    float val = logf(fmaxf(denom[idx], 1e-9f));
    // pos_partial carries the 2/ln2-scaled raw dot; restore natural-log domain with *ln2
    if (blockIdx.x == 0) val -= pos_partial[threadIdx.x] * kLn2;
    val += __shfl_xor(val, 1);  val += __shfl_xor(val, 2);  val += __shfl_xor(val, 4);
    val += __shfl_xor(val, 8);  val += __shfl_xor(val, 16); val += __shfl_xor(val, 32);
    __shared__ float acc4[4];
    if (lane == 0) acc4[w] = val;
    __syncthreads();
    if (threadIdx.x == 0)
        atomicAdd(out, (acc4[0] + acc4[1] + acc4[2] + acc4[3]) * (1.0f / kNV));
}

extern "C" void kernel_launch(void* const* d_in, const int* in_sizes, int n_in,
                              void* d_out, int out_size, void* d_ws, size_t ws_size,
                              hipStream_t stream) {
    const float* Hc = (const float*)d_in[0];   // [N, D] fp32
    const float* S  = (const float*)d_in[1];   // [N, N] fp32
    const float* Hv = (const float*)d_in[2];   // [V, N, D] fp32

    unsigned* HcB  = (unsigned*)d_ws;                            // 2 MB
    unsigned* HvB  = HcB + (size_t)kN * (kD / 2);                // 6 MB
    float*    den  = (float*)(HvB + (size_t)kV * kN * (kD / 2)); // kNV floats
    float*    posp = den + kNV;                                  // 256 floats
    float*    outF = (float*)d_out;

    hipMemsetAsync(den, 0, ((size_t)kNV + 256) * sizeof(float), stream);
    hipMemsetAsync(outF, 0, sizeof(float), stream);

    k_normalize<<<dim3((kN + kV * kN) / 4), 256, 0, stream>>>(Hc, Hv, HcB, HvB);
    k_positive<<<dim3(kNV / 4), 256, 0, stream>>>(HcB, HvB, posp);
    k_main<<<dim3(kN / 64, kN / kNChunk), dim3(256), 0, stream>>>(HcB, HvB, S, den);
    k_final<<<dim3(kNV / 256), dim3(256), 0, stream>>>(den, posp, outF);
}